// Round 2
// baseline (215.465 us; speedup 1.0000x reference)
//
#include <hip/hip_runtime.h>
#include <stdint.h>

// Problem constants (fixed by setup_inputs in the reference)
#define BATCH 32
#define HDIM  1024
#define WDIM  1024
#define H2    (HDIM / 2)
#define W2    (WDIM / 2)
#define NSTN  256                 // stations per batch
#define NBLOCKS 2048              // 8 blocks/CU * 256 CU, fully resident
#define NTHREADS (NBLOCKS * 256)  // 524288

// clang native vector: __builtin_nontemporal_load requires a native
// int/float/pointer or vector-of-such type (HIP float4 is a class — invalid).
typedef float f32x4 __attribute__((ext_vector_type(4)));

// ---------------------------------------------------------------------------
// Wave-64 + LDS block reduction (sum). Block size = 256. Result in thread 0.
// ---------------------------------------------------------------------------
__device__ __forceinline__ float blockReduceSum(float v, float* smem) {
    #pragma unroll
    for (int off = 32; off > 0; off >>= 1)
        v += __shfl_down(v, off, 64);
    const int lane = threadIdx.x & 63;
    const int wid  = threadIdx.x >> 6;
    if (lane == 0) smem[wid] = v;
    __syncthreads();
    v = (threadIdx.x < 4) ? smem[threadIdx.x] : 0.0f;
    if (wid == 0) {
        v += __shfl_down(v, 2, 64);
        v += __shfl_down(v, 1, 64);
    }
    return v;
}

// ---------------------------------------------------------------------------
// Kernel A: image MSE partials (all blocks) + station MSE partials (blocks
// 0..31). Partials to unique d_ws slots (no atomics/fences — round-2 lesson).
//
// Image loss: unit u = b*65536 + yp*128 + xg (xg: 8-px group, yp: row pair).
// Grid stride NTHREADS = 8*65536, so a thread's 4 iterations share (yp, xg)
// and differ only in b — all row indices, clamps, and x-offsets are hoisted;
// the unrolled iterations are fully independent (52 VMEM loads schedulable
// up-front; intra-thread latency hiding).
//
// This round:
//  * Chunked XCD swizzle: w = (orig&7)*256 + orig>>3 (bijective, 2048=8*256).
//    Consecutive work-units (adjacent yp, which share 2 of 3 target rows) now
//    land on the SAME XCD's L2 instead of being round-robined across 8 XCDs.
//    Each XCD owns exactly one b0 slice: 4 tgt planes = 4 MB = one L2.
//  * Nontemporal (nt) loads for pred: 128 MB zero-reuse stream no longer
//    evicts the 4 MB resident tgt working set from L2.
//
// Per 8x2-px tile: 4 pred float4 + per tgt row (3 rows): 1 aligned float4 @
// m0 + 2 clamped scalar edge loads. 13 VMEM / 16 px, ZERO shuffles, ZERO
// divergent patch branches (round-4 lesson: ds_bpermute + lane-0/63 exec
// masking ate the entire VMEM saving).
//
// jax.image.resize 'bilinear' 512->1024 (half-pixel centers):
//   even y=2m:  0.25*t[m-1] + 0.75*t[m]   (index-clamped == edge renorm)
//   odd  y=2m+1: 0.75*t[m] + 0.25*t[m+1]  (same in x)
// ---------------------------------------------------------------------------
__global__ __launch_bounds__(256) void fused_compute_kernel(
        const float* __restrict__ pred,
        const float* __restrict__ tgt,
        const int*   __restrict__ pos,
        const float* __restrict__ runoff,
        float* __restrict__ img_part,    // [NBLOCKS]
        float* __restrict__ stn_part) {  // [32]
    __shared__ float smem[4];

    // ---- station partial (blocks 0..31, one thread per station) ----
    // Keyed off the RAW blockIdx (spreads 4 station blocks per XCD).
    if (blockIdx.x < 32) {
        const int idx = blockIdx.x * 256 + threadIdx.x;   // 32*256 = B*S
        const int bb = idx >> 8;                          // NSTN = 256
        const int px = pos[idx * 2 + 0];
        const int py = pos[idx * 2 + 1];
        const float* p = pred + ((int64_t)bb << 20);
        float sum = 0.0f; int cnt = 0;
        #pragma unroll
        for (int dy = -1; dy <= 1; ++dy) {
            const int y = py + dy;
            if (y < 0 || y >= HDIM) continue;
            #pragma unroll
            for (int dx = -1; dx <= 1; ++dx) {
                const int x = px + dx;
                if (x < 0 || x >= WDIM) continue;
                sum += p[y * WDIM + x];
                cnt++;
            }
        }
        const float d = sum / (float)cnt - runoff[idx];
        const float bs = blockReduceSum(d * d, smem);
        if (threadIdx.x == 0) stn_part[blockIdx.x] = bs;
        __syncthreads();   // smem reuse hazard before img reduction
    }

    // ---- image loss: 4 independent b-iterations, hoisted geometry ----
    // Chunked XCD swizzle (blocks dispatch round-robin over 8 XCDs):
    // XCD j processes contiguous work ids [j*256, (j+1)*256).
    const int orig = blockIdx.x;
    const int w    = ((orig & 7) << 8) + (orig >> 3);   // bijective remap
    const int tid  = w * 256 + threadIdx.x;
    const int xg = tid & 127;            // 8-px x-group (wave: contiguous)
    const int yp = (tid >> 7) & 511;     // row pair
    const int b0 = tid >> 16;            // 0..7 (constant per XCD chunk)
    const int x0 = xg << 3;
    const int m0 = xg << 2;

    const int ym1 = (yp == 0)      ? 0      : yp - 1;
    const int yp1 = (yp == H2 - 1) ? H2 - 1 : yp + 1;
    const int xm1 = (m0 == 0)      ? 0      : m0 - 1;
    const int xp4 = (m0 + 4 > W2 - 1) ? W2 - 1 : m0 + 4;

    const int predoff = (yp << 11) + x0;   // (2*yp)*1024 + x0 within a batch
    const int offA = (ym1 << 9);
    const int offB = (yp  << 9);
    const int offC = (yp1 << 9);

    float img_local = 0.0f;
    #pragma unroll
    for (int i = 0; i < 4; ++i) {
        const int bb = b0 + 8 * i;
        const float* pr = pred + (bb << 20) + predoff;
        // Nontemporal: pred is a zero-reuse 128 MB stream; keep it from
        // evicting the L2-resident tgt rows.
        const f32x4* pr0 = (const f32x4*)pr;
        const f32x4* pr1 = (const f32x4*)(pr + WDIM);
        const f32x4 pe0 = __builtin_nontemporal_load(pr0);          // row 2yp
        const f32x4 pe1 = __builtin_nontemporal_load(pr0 + 1);
        const f32x4 po0 = __builtin_nontemporal_load(pr1);          // row 2yp+1
        const f32x4 po1 = __builtin_nontemporal_load(pr1 + 1);

        const float* tb = tgt + (bb << 18);
        const float* tA = tb + offA;
        const float* tB = tb + offB;
        const float* tC = tb + offC;

        const float4 a4 = *(const float4*)(tA + m0);
        const float4 b4 = *(const float4*)(tB + m0);
        const float4 c4 = *(const float4*)(tC + m0);
        const float la = tA[xm1], ra = tA[xp4];
        const float lb = tB[xm1], rb = tB[xp4];
        const float lc = tC[xm1], rc = tC[xp4];

        // vertical interp across the 6-column window [m0-1 .. m0+4]
        float e[6], o[6];
        e[0] = 0.25f * la   + 0.75f * lb;    o[0] = 0.75f * lb   + 0.25f * lc;
        e[1] = 0.25f * a4.x + 0.75f * b4.x;  o[1] = 0.75f * b4.x + 0.25f * c4.x;
        e[2] = 0.25f * a4.y + 0.75f * b4.y;  o[2] = 0.75f * b4.y + 0.25f * c4.y;
        e[3] = 0.25f * a4.z + 0.75f * b4.z;  o[3] = 0.75f * b4.z + 0.25f * c4.z;
        e[4] = 0.25f * a4.w + 0.75f * b4.w;  o[4] = 0.75f * b4.w + 0.25f * c4.w;
        e[5] = 0.25f * ra   + 0.75f * rb;    o[5] = 0.75f * rb   + 0.25f * rc;

        const float pev[8] = {pe0[0], pe0[1], pe0[2], pe0[3],
                              pe1[0], pe1[1], pe1[2], pe1[3]};
        const float pov[8] = {po0[0], po0[1], po0[2], po0[3],
                              po1[0], po1[1], po1[2], po1[3]};

        // horizontal interp (even,odd per m-col) + squared diff, 16 pixels
        #pragma unroll
        for (int k = 0; k < 4; ++k) {
            const float te0 = 0.25f * e[k]     + 0.75f * e[k + 1];
            const float te1 = 0.75f * e[k + 1] + 0.25f * e[k + 2];
            const float to0 = 0.25f * o[k]     + 0.75f * o[k + 1];
            const float to1 = 0.75f * o[k + 1] + 0.25f * o[k + 2];
            const float d0 = pev[2 * k]     - te0;
            const float d1 = pev[2 * k + 1] - te1;
            const float d2 = pov[2 * k]     - to0;
            const float d3 = pov[2 * k + 1] - to1;
            img_local += d0 * d0 + d1 * d1 + d2 * d2 + d3 * d3;
        }
    }

    const float bi = blockReduceSum(img_local, smem);
    if (threadIdx.x == 0) img_part[blockIdx.x] = bi;
}

// ---------------------------------------------------------------------------
// Kernel B: reduce 2048 img partials + 32 stn partials, write 3 outputs.
// ---------------------------------------------------------------------------
__global__ __launch_bounds__(256) void finalize_kernel(
        const float* __restrict__ img_part,
        const float* __restrict__ stn_part,
        float* __restrict__ out) {
    __shared__ float smem[4];

    float v = 0.0f;
    #pragma unroll
    for (int i = 0; i < NBLOCKS / 256; ++i)
        v += img_part[threadIdx.x + i * 256];
    const float img_sum = blockReduceSum(v, smem);
    __syncthreads();   // smem reuse

    float s = (threadIdx.x < 32) ? stn_part[threadIdx.x] : 0.0f;
    const float stn_sum = blockReduceSum(s, smem);

    if (threadIdx.x == 0) {
        const float img = img_sum * (1.0f / ((float)BATCH * HDIM * WDIM));
        const float stn = stn_sum * (1.0f / ((float)BATCH * NSTN));
        out[0] = img + 0.5f * stn;   // IMAGE_W=1.0, STATION_W=0.5
        out[1] = img;
        out[2] = stn;
    }
}

extern "C" void kernel_launch(void* const* d_in, const int* in_sizes, int n_in,
                              void* d_out, int out_size, void* d_ws, size_t ws_size,
                              hipStream_t stream) {
    const float* pred   = (const float*)d_in[0];
    const float* tgt    = (const float*)d_in[1];
    const int*   pos    = (const int*)d_in[2];
    const float* runoff = (const float*)d_in[3];
    float* out = (float*)d_out;
    float* img_part = (float*)d_ws;            // [NBLOCKS]
    float* stn_part = img_part + NBLOCKS;      // [32]

    // No memset needed: every partial slot is written unconditionally.
    fused_compute_kernel<<<NBLOCKS, 256, 0, stream>>>(pred, tgt, pos, runoff,
                                                      img_part, stn_part);
    finalize_kernel<<<1, 256, 0, stream>>>(img_part, stn_part, out);
}

// Round 3
// 210.921 us; speedup vs baseline: 1.0215x; 1.0215x over previous
//
#include <hip/hip_runtime.h>
#include <stdint.h>

// Problem constants (fixed by setup_inputs in the reference)
#define BATCH 32
#define HDIM  1024
#define WDIM  1024
#define H2    (HDIM / 2)
#define W2    (WDIM / 2)
#define NSTN  256                 // stations per batch
#define NBLOCKS 8192              // 1 tile/thread: 8192*256*16px = 32*1024*1024
// clang native vector: __builtin_nontemporal_load requires a native
// int/float/pointer or vector-of-such type (HIP float4 is a class — invalid).
typedef float f32x4 __attribute__((ext_vector_type(4)));

// ---------------------------------------------------------------------------
// Wave-64 + LDS block reduction (sum). Block size = 256. Result in thread 0.
// ---------------------------------------------------------------------------
__device__ __forceinline__ float blockReduceSum(float v, float* smem) {
    #pragma unroll
    for (int off = 32; off > 0; off >>= 1)
        v += __shfl_down(v, off, 64);
    const int lane = threadIdx.x & 63;
    const int wid  = threadIdx.x >> 6;
    if (lane == 0) smem[wid] = v;
    __syncthreads();
    v = (threadIdx.x < 4) ? smem[threadIdx.x] : 0.0f;
    if (wid == 0) {
        v += __shfl_down(v, 2, 64);
        v += __shfl_down(v, 1, 64);
    }
    return v;
}

// ---------------------------------------------------------------------------
// Kernel A: image MSE partials (all blocks) + station MSE partials (blocks
// 0..31). Partials to unique d_ws slots (no atomics/fences).
//
// ROUND 3 RESTRUCTURE — occupancy over ILP:
//   Round-2 post-mortem: 4x-unrolled body holds ~136 VGPRs of load data
//   alone -> >128 VGPR -> 2 waves/SIMD. Little's law: 6.3 TB/s needs
//   ~9-10 KB outstanding/CU; 2 waves/SIMD delivered ~4-5 KB -> ~3 TB/s.
//   Now: ONE 8x2-px tile per thread (13 loads, ~34 data regs), 8192 blocks,
//   __launch_bounds__(256,6) -> target 6 waves/SIMD (24 waves/CU, ~13 KB
//   in flight). TLP replaces ILP; VALU cost of re-computing geometry per
//   thread is ~2 us chip-wide (negligible vs the latency-hiding win).
//
// Per 8x2-px tile: 4 pred float4 (nontemporal: zero-reuse 128 MB stream)
// + per tgt row (3 rows): 1 aligned float4 @ m0 + 2 clamped scalar edge
// loads. tgt re-reads are L3-resident (34 MB << 256 MB L3) — not HBM
// traffic (round-2 lesson: XCD/L2 tuning for tgt is a no-op).
//
// Chunked XCD swizzle kept (8192 = 8*1024, bijective): each XCD owns one
// contiguous work range -> 4 tgt planes (4 MB) per XCD L2.
//
// jax.image.resize 'bilinear' 512->1024 (half-pixel centers):
//   even y=2m:  0.25*t[m-1] + 0.75*t[m]   (index-clamped == edge renorm)
//   odd  y=2m+1: 0.75*t[m] + 0.25*t[m+1]  (same in x)
// ---------------------------------------------------------------------------
__global__ __launch_bounds__(256, 6) void fused_compute_kernel(
        const float* __restrict__ pred,
        const float* __restrict__ tgt,
        const int*   __restrict__ pos,
        const float* __restrict__ runoff,
        float* __restrict__ img_part,    // [NBLOCKS]
        float* __restrict__ stn_part) {  // [32]
    __shared__ float smem[4];

    // ---- station partial (blocks 0..31, one thread per station) ----
    // Keyed off the RAW blockIdx (spreads station blocks across XCDs).
    if (blockIdx.x < 32) {
        const int idx = blockIdx.x * 256 + threadIdx.x;   // 32*256 = B*S
        const int bb = idx >> 8;                          // NSTN = 256
        const int px = pos[idx * 2 + 0];
        const int py = pos[idx * 2 + 1];
        const float* p = pred + ((int64_t)bb << 20);
        float sum = 0.0f; int cnt = 0;
        #pragma unroll
        for (int dy = -1; dy <= 1; ++dy) {
            const int y = py + dy;
            if (y < 0 || y >= HDIM) continue;
            #pragma unroll
            for (int dx = -1; dx <= 1; ++dx) {
                const int x = px + dx;
                if (x < 0 || x >= WDIM) continue;
                sum += p[y * WDIM + x];
                cnt++;
            }
        }
        const float d = sum / (float)cnt - runoff[idx];
        const float bs = blockReduceSum(d * d, smem);
        if (threadIdx.x == 0) stn_part[blockIdx.x] = bs;
        __syncthreads();   // smem reuse hazard before img reduction
    }

    // ---- image loss: ONE 8x2-px tile per thread ----
    // Chunked XCD swizzle (blocks dispatch round-robin over 8 XCDs):
    // XCD j processes contiguous work ids [j*1024, (j+1)*1024).
    const int orig = blockIdx.x;
    const int w    = ((orig & 7) << 10) + (orig >> 3);  // bijective remap
    const int tid  = w * 256 + threadIdx.x;
    const int xg = tid & 127;            // 8-px x-group (wave: contiguous)
    const int yp = (tid >> 7) & 511;     // row pair
    const int bb = tid >> 16;            // batch 0..31 (4 per XCD chunk)
    const int x0 = xg << 3;
    const int m0 = xg << 2;

    const int ym1 = (yp == 0)      ? 0      : yp - 1;
    const int yp1 = (yp == H2 - 1) ? H2 - 1 : yp + 1;
    const int xm1 = (m0 == 0)      ? 0      : m0 - 1;
    const int xp4 = (m0 + 4 > W2 - 1) ? W2 - 1 : m0 + 4;

    const float* pr = pred + (bb << 20) + (yp << 11) + x0;
    const f32x4* pr0 = (const f32x4*)pr;
    const f32x4* pr1 = (const f32x4*)(pr + WDIM);
    const f32x4 pe0 = __builtin_nontemporal_load(pr0);          // row 2yp
    const f32x4 pe1 = __builtin_nontemporal_load(pr0 + 1);
    const f32x4 po0 = __builtin_nontemporal_load(pr1);          // row 2yp+1
    const f32x4 po1 = __builtin_nontemporal_load(pr1 + 1);

    const float* tb = tgt + (bb << 18);
    const float* tA = tb + (ym1 << 9);
    const float* tB = tb + (yp  << 9);
    const float* tC = tb + (yp1 << 9);

    const float4 a4 = *(const float4*)(tA + m0);
    const float4 b4 = *(const float4*)(tB + m0);
    const float4 c4 = *(const float4*)(tC + m0);
    const float la = tA[xm1], ra = tA[xp4];
    const float lb = tB[xm1], rb = tB[xp4];
    const float lc = tC[xm1], rc = tC[xp4];

    // vertical interp across the 6-column window [m0-1 .. m0+4]
    float e[6], o[6];
    e[0] = 0.25f * la   + 0.75f * lb;    o[0] = 0.75f * lb   + 0.25f * lc;
    e[1] = 0.25f * a4.x + 0.75f * b4.x;  o[1] = 0.75f * b4.x + 0.25f * c4.x;
    e[2] = 0.25f * a4.y + 0.75f * b4.y;  o[2] = 0.75f * b4.y + 0.25f * c4.y;
    e[3] = 0.25f * a4.z + 0.75f * b4.z;  o[3] = 0.75f * b4.z + 0.25f * c4.z;
    e[4] = 0.25f * a4.w + 0.75f * b4.w;  o[4] = 0.75f * b4.w + 0.25f * c4.w;
    e[5] = 0.25f * ra   + 0.75f * rb;    o[5] = 0.75f * rb   + 0.25f * rc;

    const float pev[8] = {pe0[0], pe0[1], pe0[2], pe0[3],
                          pe1[0], pe1[1], pe1[2], pe1[3]};
    const float pov[8] = {po0[0], po0[1], po0[2], po0[3],
                          po1[0], po1[1], po1[2], po1[3]};

    // horizontal interp (even,odd per m-col) + squared diff, 16 pixels
    float img_local = 0.0f;
    #pragma unroll
    for (int k = 0; k < 4; ++k) {
        const float te0 = 0.25f * e[k]     + 0.75f * e[k + 1];
        const float te1 = 0.75f * e[k + 1] + 0.25f * e[k + 2];
        const float to0 = 0.25f * o[k]     + 0.75f * o[k + 1];
        const float to1 = 0.75f * o[k + 1] + 0.25f * o[k + 2];
        const float d0 = pev[2 * k]     - te0;
        const float d1 = pev[2 * k + 1] - te1;
        const float d2 = pov[2 * k]     - to0;
        const float d3 = pov[2 * k + 1] - to1;
        img_local += d0 * d0 + d1 * d1 + d2 * d2 + d3 * d3;
    }

    const float bi = blockReduceSum(img_local, smem);
    if (threadIdx.x == 0) img_part[blockIdx.x] = bi;
}

// ---------------------------------------------------------------------------
// Kernel B: reduce 8192 img partials + 32 stn partials, write 3 outputs.
// ---------------------------------------------------------------------------
__global__ __launch_bounds__(256) void finalize_kernel(
        const float* __restrict__ img_part,
        const float* __restrict__ stn_part,
        float* __restrict__ out) {
    __shared__ float smem[4];

    float v = 0.0f;
    #pragma unroll
    for (int i = 0; i < NBLOCKS / 256; ++i)
        v += img_part[threadIdx.x + i * 256];
    const float img_sum = blockReduceSum(v, smem);
    __syncthreads();   // smem reuse

    float s = (threadIdx.x < 32) ? stn_part[threadIdx.x] : 0.0f;
    const float stn_sum = blockReduceSum(s, smem);

    if (threadIdx.x == 0) {
        const float img = img_sum * (1.0f / ((float)BATCH * HDIM * WDIM));
        const float stn = stn_sum * (1.0f / ((float)BATCH * NSTN));
        out[0] = img + 0.5f * stn;   // IMAGE_W=1.0, STATION_W=0.5
        out[1] = img;
        out[2] = stn;
    }
}

extern "C" void kernel_launch(void* const* d_in, const int* in_sizes, int n_in,
                              void* d_out, int out_size, void* d_ws, size_t ws_size,
                              hipStream_t stream) {
    const float* pred   = (const float*)d_in[0];
    const float* tgt    = (const float*)d_in[1];
    const int*   pos    = (const int*)d_in[2];
    const float* runoff = (const float*)d_in[3];
    float* out = (float*)d_out;
    float* img_part = (float*)d_ws;            // [NBLOCKS]
    float* stn_part = img_part + NBLOCKS;      // [32]

    // No memset needed: every partial slot is written unconditionally.
    fused_compute_kernel<<<NBLOCKS, 256, 0, stream>>>(pred, tgt, pos, runoff,
                                                      img_part, stn_part);
    finalize_kernel<<<1, 256, 0, stream>>>(img_part, stn_part, out);
}

// Round 5
// 204.724 us; speedup vs baseline: 1.0525x; 1.0303x over previous
//
#include <hip/hip_runtime.h>
#include <stdint.h>

// Problem constants (fixed by setup_inputs in the reference)
#define BATCH 32
#define HDIM  1024
#define WDIM  1024
#define H2    (HDIM / 2)
#define W2    (WDIM / 2)
#define NSTN  256                  // stations per batch
#define NBLOCKS 16384              // 4x2 px/thread: 16384*256*8px = 32*1024*1024

// clang native vectors. __builtin_nontemporal_load needs a native vector
// (HIP float4 is a class — invalid). The aligned(4) variant lets us do
// dword-aligned (unaligned-16) dwordx4 loads of the tgt window legally.
typedef float f32x4  __attribute__((ext_vector_type(4)));
typedef float f32x4u __attribute__((ext_vector_type(4), aligned(4)));

// ---------------------------------------------------------------------------
// Wave-64 + LDS block reduction (sum). Block size = 256. Result in thread 0.
// ---------------------------------------------------------------------------
__device__ __forceinline__ float blockReduceSum(float v, float* smem) {
    #pragma unroll
    for (int off = 32; off > 0; off >>= 1)
        v += __shfl_down(v, off, 64);
    const int lane = threadIdx.x & 63;
    const int wid  = threadIdx.x >> 6;
    if (lane == 0) smem[wid] = v;
    __syncthreads();
    v = (threadIdx.x < 4) ? smem[threadIdx.x] : 0.0f;
    if (wid == 0) {
        v += __shfl_down(v, 2, 64);
        v += __shfl_down(v, 1, 64);
    }
    return v;
}

// ---------------------------------------------------------------------------
// Kernel A: image MSE partials (all blocks) + station MSE partials (blocks
// 0..31). Partials to unique d_ws slots (no atomics/fences).
//
// ROUND 4/5 RESTRUCTURE — fewer VMEM instructions, max occupancy:
//   Round-3 post-mortem: in-flight BYTES were never the limit (any config
//   has >10 KB/CU outstanding); the limiter scales with VMEM instruction
//   count / L1-TA request rate. Thread shape: 4x2 px.
//     * 5 VMEM/thread (2 pred + 3 tgt) vs 13 — 0.63 vs 0.81 instr/px, and
//       ZERO scalar edge loads: per tgt row ONE dword-aligned dwordx4
//       covers the whole 4-col window [m0-1..m0+2]; x-clamping is done
//       with per-lane cndmask selects on the loaded components.
//     * pred loads fully contiguous: 16 B/lane, stride 16 across lanes
//       (old shape had 16 B gaps -> 2x line requests per instr).
//     * yp/bb are wave-uniform -> row bases in SGPRs; ~50 VGPR ->
//       8 waves/SIMD natural. launch_bounds(256,6) caps VGPR at 85 (no
//       spill risk) while still permitting 8 waves/SIMD.
//
// tgt re-reads are L3/L2-resident (34 MB << 256 MB L3) — HBM traffic is
// pred 134 MB + tgt 34 MB = 168 MB -> 27 us floor at 6.3 TB/s.
//
// Chunked XCD swizzle kept (16384 = 8*2048, bijective).
//
// jax.image.resize 'bilinear' 512->1024 (half-pixel centers):
//   even y=2m:  0.25*t[m-1] + 0.75*t[m]   (index-clamped == edge renorm)
//   odd  y=2m+1: 0.75*t[m] + 0.25*t[m+1]  (same in x)
// ---------------------------------------------------------------------------

// Extract the 4-column window [m0-1 .. m0+2] (x-clamped) from the one
// dwordx4 loaded at tL. Three cases, all verified:
//  interior (tL=m0-1): L=[m0-1..m0+2]        -> (L.x, L.y, L.z, L.w)
//  isL (xg==0, tL=0):  L=[t0..t3], want (t0,t0,t1,t2)   -> (L.x,L.x,L.y,L.z)
//  isR (xg==255,tL=508): L=[508..511], want (509,510,511,511)
//                                            -> (L.y,L.z,L.w,L.w)
__device__ __forceinline__ void selcols(const f32x4u L, bool isL, bool isR,
                                        float c[4]) {
    c[0] = isR ? L.y : L.x;
    c[1] = isL ? L.x : (isR ? L.z : L.y);
    c[2] = isL ? L.y : (isR ? L.w : L.z);
    c[3] = isL ? L.z : L.w;
}

__global__ __launch_bounds__(256, 6) void fused_compute_kernel(
        const float* __restrict__ pred,
        const float* __restrict__ tgt,
        const int*   __restrict__ pos,
        const float* __restrict__ runoff,
        float* __restrict__ img_part,    // [NBLOCKS]
        float* __restrict__ stn_part) {  // [32]
    __shared__ float smem[4];

    // ---- station partial (blocks 0..31, one thread per station) ----
    if (blockIdx.x < 32) {
        const int idx = blockIdx.x * 256 + threadIdx.x;   // 32*256 = B*S
        const int bb = idx >> 8;                          // NSTN = 256
        const int px = pos[idx * 2 + 0];
        const int py = pos[idx * 2 + 1];
        const float* p = pred + ((int64_t)bb << 20);
        float sum = 0.0f; int cnt = 0;
        #pragma unroll
        for (int dy = -1; dy <= 1; ++dy) {
            const int y = py + dy;
            if (y < 0 || y >= HDIM) continue;
            #pragma unroll
            for (int dx = -1; dx <= 1; ++dx) {
                const int x = px + dx;
                if (x < 0 || x >= WDIM) continue;
                sum += p[y * WDIM + x];
                cnt++;
            }
        }
        const float d = sum / (float)cnt - runoff[idx];
        const float bs = blockReduceSum(d * d, smem);
        if (threadIdx.x == 0) stn_part[blockIdx.x] = bs;
        __syncthreads();   // smem reuse hazard before img reduction
    }

    // ---- image loss: ONE 4x2-px tile per thread ----
    // Chunked XCD swizzle: XCD j gets contiguous work ids [j*2048,(j+1)*2048)
    const int orig = blockIdx.x;
    const int w    = ((orig & 7) << 11) + (orig >> 3);  // bijective remap
    const int tid  = w * 256 + threadIdx.x;
    const int xg = tid & 255;            // 4-px x-group (wave: contiguous)
    const int yp = (tid >> 8) & 511;     // row pair (wave-uniform)
    const int bb = tid >> 17;            // batch 0..31 (wave-uniform)
    const int x0 = xg << 2;              // pred x
    const int m0 = xg << 1;              // tgt col of first even px

    const int ym1 = (yp == 0)      ? 0      : yp - 1;
    const int yp1 = (yp == H2 - 1) ? H2 - 1 : yp + 1;
    const bool isL = (xg == 0);
    const bool isR = (xg == 255);
    const int tL = isL ? 0 : (isR ? (W2 - 4) : (m0 - 1));

    // pred rows 2yp, 2yp+1 @ x0..x0+3 (nontemporal: zero-reuse 128 MB stream)
    const float* pr = pred + (bb << 20) + (yp << 11) + x0;
    const f32x4 pe = __builtin_nontemporal_load((const f32x4*)pr);
    const f32x4 po = __builtin_nontemporal_load((const f32x4*)(pr + WDIM));

    // tgt rows A=yp-1, B=yp, C=yp+1: one dwordx4 each at tL
    const float* tb = tgt + (bb << 18);
    const f32x4u A = *(const f32x4u*)(tb + (ym1 << 9) + tL);
    const f32x4u Bv = *(const f32x4u*)(tb + (yp  << 9) + tL);
    const f32x4u C = *(const f32x4u*)(tb + (yp1 << 9) + tL);

    float a[4], b[4], c[4];
    selcols(A, isL, isR, a);
    selcols(Bv, isL, isR, b);
    selcols(C, isL, isR, c);

    // vertical interp: e = even output row (2yp), o = odd (2yp+1)
    float e[4], o[4];
    #pragma unroll
    for (int j = 0; j < 4; ++j) {
        e[j] = 0.25f * a[j] + 0.75f * b[j];
        o[j] = 0.75f * b[j] + 0.25f * c[j];
    }

    // horizontal interp + squared diff, 8 pixels
    // px0 x=2m0   : 0.25e0+0.75e1 | px1 x=2m0+1: 0.75e1+0.25e2
    // px2 x=2m0+2 : 0.25e1+0.75e2 | px3 x=2m0+3: 0.75e2+0.25e3
    const float te0 = 0.25f * e[0] + 0.75f * e[1];
    const float te1 = 0.75f * e[1] + 0.25f * e[2];
    const float te2 = 0.25f * e[1] + 0.75f * e[2];
    const float te3 = 0.75f * e[2] + 0.25f * e[3];
    const float to0 = 0.25f * o[0] + 0.75f * o[1];
    const float to1 = 0.75f * o[1] + 0.25f * o[2];
    const float to2 = 0.25f * o[1] + 0.75f * o[2];
    const float to3 = 0.75f * o[2] + 0.25f * o[3];

    const float d0 = pe.x - te0, d1 = pe.y - te1;
    const float d2 = pe.z - te2, d3 = pe.w - te3;
    const float d4 = po.x - to0, d5 = po.y - to1;
    const float d6 = po.z - to2, d7 = po.w - to3;

    const float img_local = d0 * d0 + d1 * d1 + d2 * d2 + d3 * d3
                          + d4 * d4 + d5 * d5 + d6 * d6 + d7 * d7;

    const float bi = blockReduceSum(img_local, smem);
    if (threadIdx.x == 0) img_part[blockIdx.x] = bi;
}

// ---------------------------------------------------------------------------
// Kernel B: reduce 16384 img partials + 32 stn partials, write 3 outputs.
// ---------------------------------------------------------------------------
__global__ __launch_bounds__(256) void finalize_kernel(
        const float* __restrict__ img_part,
        const float* __restrict__ stn_part,
        float* __restrict__ out) {
    __shared__ float smem[4];

    // 16384 floats = 4096 float4; thread reads 16 coalesced float4s
    const f32x4* p4 = (const f32x4*)img_part;
    float v = 0.0f;
    #pragma unroll
    for (int i = 0; i < 16; ++i) {
        const f32x4 x = p4[threadIdx.x + i * 256];
        v += x.x + x.y + x.z + x.w;
    }
    const float img_sum = blockReduceSum(v, smem);
    __syncthreads();   // smem reuse

    float s = (threadIdx.x < 32) ? stn_part[threadIdx.x] : 0.0f;
    const float stn_sum = blockReduceSum(s, smem);

    if (threadIdx.x == 0) {
        const float img = img_sum * (1.0f / ((float)BATCH * HDIM * WDIM));
        const float stn = stn_sum * (1.0f / ((float)BATCH * NSTN));
        out[0] = img + 0.5f * stn;   // IMAGE_W=1.0, STATION_W=0.5
        out[1] = img;
        out[2] = stn;
    }
}

extern "C" void kernel_launch(void* const* d_in, const int* in_sizes, int n_in,
                              void* d_out, int out_size, void* d_ws, size_t ws_size,
                              hipStream_t stream) {
    const float* pred   = (const float*)d_in[0];
    const float* tgt    = (const float*)d_in[1];
    const int*   pos    = (const int*)d_in[2];
    const float* runoff = (const float*)d_in[3];
    float* out = (float*)d_out;
    float* img_part = (float*)d_ws;            // [NBLOCKS]
    float* stn_part = img_part + NBLOCKS;      // [32]

    // No memset needed: every partial slot is written unconditionally.
    fused_compute_kernel<<<NBLOCKS, 256, 0, stream>>>(pred, tgt, pos, runoff,
                                                      img_part, stn_part);
    finalize_kernel<<<1, 256, 0, stream>>>(img_part, stn_part, out);
}